// Round 9
// baseline (230.121 us; speedup 1.0000x reference)
//
#include <hip/hip_runtime.h>
#include <hip/hip_cooperative_groups.h>
#include <math.h>

namespace cg = cooperative_groups;

// Problem constants (fixed by the reference setup_inputs)
#define BB 4
#define TT 4096
#define SS 4096
#define EE 512
#define HH 64
#define NN 128          // Chebyshev nodes / polynomial degree
#define XR 6.0f         // interpolation half-range for x

// Workspace layout (floats), NO aliasing (~8.5 MB):
//  Opart  : [B][64][N][H]  ws + 0      (2M)  partial O tiles
//  Cmat   : [N][N]         ws + 2M     (16384)
//  qnA    : bf16 A-frags   +16384      (4096 float-slots = 8192 bf16)
//  Wfrag  : bf16 B-frags   +4096       (32768 float-slots = 65536 bf16)
//  Sm_part: [B][32][N]     +32768      (16384)
//  ynode  : [B][N]         +16384      (512)

typedef __attribute__((ext_vector_type(8))) __bf16 bf16x8;
typedef __attribute__((ext_vector_type(16))) float f32x16;

__device__ __forceinline__ unsigned short f2b(float f) {
  unsigned int u = __float_as_uint(f);
  return (unsigned short)((u + 0x7FFFu + ((u >> 16) & 1u)) >> 16);  // RNE
}

// ---------------------------------------------------------------------------
// ONE cooperative kernel, 256 blocks x 256 threads (co-resident: 1 block/CU).
// grid.sync() replaces the former 4-dispatch pipeline's 3 launch boundaries.
//
// phase 0 (block-partitioned prep):
//   blk [0,128)   : Sm_part[b][chunk][m] = sum_{128 t} cos(m*acos(xhat_t))
//   blk [128,160) : qnA bf16 A-frags of qn[j][h] = tanh(x_j*qw[h]+qb[h])
//   blk [160,224) : Wfrag pack (kw||vw fp32 -> MFMA B-frag bf16)
//   blk [224,256) : Cmat[m][j] = cos(m*pi*(j+.5)/N) (2 entries/thread)
// phase 1 (kvattn, R8-verified body): block = 64-row s-chunk; emb->bf16 LDS
//   A-frags; kv MFMA; tanh epilogue to ktB/vB B-frags in LDS; GEMM1 MFMA;
//   exp + Z reduce (wq recomputed per block); GEMM2 MFMA -> Opart.
// phase 2 (oy): block = (b, 2 j's); 16-sc sums; LDS reduce; tanh*pw; -> ynode
// phase 3 (final): block = 64 t's; coef[b] DCT in LDS; double Clenshaw -> y
//
// LDS: single 69120-B pool, phase-aliased. A_lds needs the full 64 KB
// (64x512 bf16) during phase-1 staging (R7's NaN was sizing it at 36 KB).
// ---------------------------------------------------------------------------
__global__ __launch_bounds__(256) void mega_kernel(
    const float* __restrict__ x, const float* __restrict__ emb,
    const float* __restrict__ kw, const float* __restrict__ kb,
    const float* __restrict__ qw, const float* __restrict__ qb,
    const float* __restrict__ vw, const float* __restrict__ pw,
    const float* __restrict__ pb, unsigned int* __restrict__ Wfrag,
    float* __restrict__ Cmat, unsigned short* __restrict__ qnA,
    float* __restrict__ Sm_part, float* __restrict__ Opart,
    float* __restrict__ ynode, float* __restrict__ y) {
  cg::grid_group grid = cg::this_grid();
  __shared__ __align__(16) char smem[69120];
  const int tid = threadIdx.x;
  const int blk = blockIdx.x;

  // ================= phase 0: distributed prep =================
  if (blk < 128) {
    float* theta = (float*)(smem + 65536);
    int b = blk >> 5, chunk = blk & 31, t0 = chunk * 128;
    if (tid < 128) {
      float xh = x[b * TT + t0 + tid] * (1.0f / XR);
      xh = fminf(1.0f, fmaxf(-1.0f, xh));
      theta[tid] = acosf(xh);
    }
    __syncthreads();
    if (tid < 128) {
      float m = (float)tid;
      float acc = 0.f;
#pragma unroll 8
      for (int i = 0; i < 128; ++i) acc += cosf(m * theta[i]);
      Sm_part[(b * 32 + chunk) * NN + tid] = acc;
    }
  } else if (blk < 160) {
    int idx = (blk - 128) * 256 + tid;  // [0, 8192)
    int h = idx & 63;
    int j = idx >> 6;
    double th = M_PI * (j + 0.5) / NN;
    float xj = (float)(XR * cos(th));
    float val = tanhf(fmaf(xj, qw[h], qb[h]));
    // A-frag position for element (m=j, k=h):
    int pos = (((j >> 5) * 4 + (h >> 4)) * 64 + (j & 31) + 32 * ((h >> 3) & 1)) * 8 +
              (h & 7);
    qnA[pos] = f2b(val);
  } else if (blk < 224) {
    // Wfrag pack: ((nblk*32 + kstep)*64 + lane)*8 + j  (bf16 units)
    int idx = (blk - 160) * 256 + tid;  // [0, 16384)
    int jq = idx & 1;
    int l = (idx >> 1) & 63;
    int ks = (idx >> 7) & 31;
    int nb = idx >> 12;
    int n = nb * 32 + (l & 31);
    int k = ks * 16 + (l >> 5) * 8 + jq * 4;
    const float* row = (n < HH) ? (kw + n * EE + k) : (vw + (n - HH) * EE + k);
    float4 wv = *(const float4*)row;
    Wfrag[idx * 2] = (unsigned int)f2b(wv.x) | ((unsigned int)f2b(wv.y) << 16);
    Wfrag[idx * 2 + 1] =
        (unsigned int)f2b(wv.z) | ((unsigned int)f2b(wv.w) << 16);
  } else {
    int idx = (blk - 224) * 256 + tid;  // [0, 8192); 2 entries each
#pragma unroll
    for (int r = 0; r < 2; ++r) {
      int id2 = idx + r * 8192;
      int m = id2 >> 7;
      int j = id2 & (NN - 1);
      Cmat[id2] = (float)cos((double)m * (M_PI * (j + 0.5) / NN));
    }
  }
  grid.sync();

  // ================= phase 1: kvattn (R8-verified) =================
  {
    unsigned short* A_lds = (unsigned short*)smem;         // 65536 B (p0/p1)
    unsigned short* ktB = (unsigned short*)smem;           // 8192 B  (p2+)
    unsigned short* vB = (unsigned short*)(smem + 8192);   // 8192 B  (p2+)
    unsigned short* eA = (unsigned short*)(smem + 16384);  // 16384 B (p4)
    float* zred = (float*)(smem + 65536);                  // 64*9 floats
    float* wql = (float*)(smem + 67840);                   // 128
    float* izl = (float*)(smem + 68352);                   // 64
    float* sml = (float*)(smem + 68608);                   // 128

    const int row0 = blk * 64;  // [0, B*S)
    const int bb = row0 >> 12;
    const int sc = (row0 >> 6) & 63;

    // ---- p0: stage A (64 rows x 512 k), fp32 -> bf16 frags ----
#pragma unroll
    for (int mb = 0; mb < 2; ++mb) {
      int m = tid >> 3;  // 0..31 local row
      int c8 = tid & 7;
      const float* src = emb + (size_t)(row0 + mb * 32 + m) * EE;
      unsigned short* dst = A_lds + mb * 16384;
#pragma unroll
      for (int it = 0; it < 16; ++it) {
        int k = (c8 + it * 8) * 4;
        float4 v = *(const float4*)(src + k);
        int kstep = k >> 4;
        int lane = m + 32 * ((k >> 3) & 1);
        int j = k & 7;
        unsigned int lo =
            (unsigned int)f2b(v.x) | ((unsigned int)f2b(v.y) << 16);
        unsigned int hi =
            (unsigned int)f2b(v.z) | ((unsigned int)f2b(v.w) << 16);
        *(uint2*)&dst[(kstep * 64 + lane) * 8 + j] = make_uint2(lo, hi);
      }
    }
    // p0b: Sm chunk-reduce (tid<128)
    if (tid < 128) {
      float s = 0.f;
#pragma unroll 8
      for (int c = 0; c < 32; ++c) s += Sm_part[(bb * 32 + c) * NN + tid];
      sml[tid] = s;
    }
    __syncthreads();
    // p0c: wq[j] (tid<128; fp32 — error ~1e-6 rel, audited)
    if (tid < 128) {
      float acc = sml[0] * (1.0f / NN);
      for (int m = 1; m < NN; ++m)
        acc = fmaf(sml[m] * (2.0f / NN), Cmat[m * NN + tid], acc);
      wql[tid] = acc;
    }

    // ---- p1: kv MFMA ----
    const int w = tid >> 6;  // wave 0..3 (0,1=K cols; 2,3=V cols)
    const int lane = tid & 63;
    f32x16 acc0 = {}, acc1 = {};
    const bf16x8* Bf = (const bf16x8*)Wfrag;
#pragma unroll 4
    for (int kstep = 0; kstep < 32; ++kstep) {
      bf16x8 bfr = Bf[(w * 32 + kstep) * 64 + lane];
      bf16x8 a0 = *(const bf16x8*)&A_lds[(kstep * 64 + lane) * 8];
      bf16x8 a1 = *(const bf16x8*)&A_lds[16384 + (kstep * 64 + lane) * 8];
      acc0 = __builtin_amdgcn_mfma_f32_32x32x16_bf16(a0, bfr, acc0, 0, 0, 0);
      acc1 = __builtin_amdgcn_mfma_f32_32x32x16_bf16(a1, bfr, acc1, 0, 0, 0);
    }
    __syncthreads();  // A_lds dead; ktB/vB/eA alias it

    // ---- p2: epilogue -> bf16 B-frags in LDS ----
    {
      const int n = w * 32 + (lane & 31);
      if (w < 2) {  // K half: element (k=h=n, n_dim=s)
        float kbv = kb[n];
        const int ks_h = n >> 4;
        const int off_h = 32 * ((n >> 3) & 1);
        const int jj_h = n & 7;
#pragma unroll
        for (int reg = 0; reg < 16; ++reg) {
          int sl = (reg & 3) + 8 * (reg >> 2) + 4 * (lane >> 5);  // s in [0,32)
          ktB[(ks_h * 64 + sl + off_h) * 8 + jj_h] =
              f2b(tanhf(acc0[reg] + kbv));
          ktB[((4 + ks_h) * 64 + sl + off_h) * 8 + jj_h] =
              f2b(tanhf(acc1[reg] + kbv));
        }
      } else {  // V half: element (k=s, n_dim=h)
        int h = n - 64;
        const int nb_h = h >> 5;
        const int lm = h & 31;
#pragma unroll
        for (int reg = 0; reg < 16; ++reg) {
          int sl = (reg & 3) + 8 * (reg >> 2) + 4 * (lane >> 5);
          int s1 = sl + 32;
          vB[((nb_h * 4 + (sl >> 4)) * 64 + lm + 32 * ((sl >> 3) & 1)) * 8 +
             (sl & 7)] = f2b(tanhf(acc0[reg]));
          vB[((nb_h * 4 + (s1 >> 4)) * 64 + lm + 32 * ((s1 >> 3) & 1)) * 8 +
             (s1 & 7)] = f2b(tanhf(acc1[reg]));
        }
      }
    }
    __syncthreads();

    // ---- p3: GEMM1 MFMA: l[j][s], j-block = w ----
    f32x16 l0 = {}, l1 = {};
#pragma unroll
    for (int ks = 0; ks < 4; ++ks) {
      bf16x8 a = *(const bf16x8*)(qnA + ((w * 4 + ks) * 64 + lane) * 8);
      bf16x8 b0 = *(const bf16x8*)&ktB[(ks * 64 + lane) * 8];
      bf16x8 b1 = *(const bf16x8*)&ktB[((4 + ks) * 64 + lane) * 8];
      l0 = __builtin_amdgcn_mfma_f32_32x32x16_bf16(a, b0, l0, 0, 0, 0);
      l1 = __builtin_amdgcn_mfma_f32_32x32x16_bf16(a, b1, l1, 0, 0, 0);
    }
    // exp + Z partials (j = w*32 + (reg&3)+8*(reg>>2)+4*(lane>>5))
    float e0[16], e1[16];
    float zp0 = 0.f, zp1 = 0.f;
#pragma unroll
    for (int r = 0; r < 4; ++r) {
      float4 wq4 = *(const float4*)&wql[w * 32 + 8 * r + 4 * (lane >> 5)];
      float wa[4] = {wq4.x, wq4.y, wq4.z, wq4.w};
#pragma unroll
      for (int c = 0; c < 4; ++c) {
        int reg = 4 * r + c;
        e0[reg] = __expf(l0[reg] * 0.125f);
        e1[reg] = __expf(l1[reg] * 0.125f);
        zp0 = fmaf(wa[c], e0[reg], zp0);
        zp1 = fmaf(wa[c], e1[reg], zp1);
      }
    }
    zred[(lane & 31) * 9 + w * 2 + (lane >> 5)] = zp0;
    zred[(32 + (lane & 31)) * 9 + w * 2 + (lane >> 5)] = zp1;
    __syncthreads();
    if (tid < 64) {
      float sum = 0.f;
#pragma unroll
      for (int k = 0; k < 8; ++k) sum += zred[tid * 9 + k];
      izl[tid] = 1.0f / sum;
    }
    __syncthreads();

    // ---- p4: pack e*invZ -> eA (A-frag: m=j, k=s), then GEMM2 MFMA ----
    {
      const int sA = lane & 31, sB = 32 + (lane & 31);
      const float izA = izl[sA], izB = izl[sB];
      const int ksA = sA >> 4, oA = 32 * ((sA >> 3) & 1), jA = sA & 7;
      const int ksB = sB >> 4, oB = 32 * ((sB >> 3) & 1), jB = sB & 7;
#pragma unroll
      for (int reg = 0; reg < 16; ++reg) {
        int jl = (reg & 3) + 8 * (reg >> 2) + 4 * (lane >> 5);  // j & 31
        eA[((w * 4 + ksA) * 64 + jl + oA) * 8 + jA] = f2b(e0[reg] * izA);
        eA[((w * 4 + ksB) * 64 + jl + oB) * 8 + jB] = f2b(e1[reg] * izB);
      }
    }
    __syncthreads();
    f32x16 o0 = {}, o1 = {};
#pragma unroll
    for (int ks = 0; ks < 4; ++ks) {
      bf16x8 a = *(const bf16x8*)&eA[((w * 4 + ks) * 64 + lane) * 8];
      bf16x8 b0 = *(const bf16x8*)&vB[(ks * 64 + lane) * 8];
      bf16x8 b1 = *(const bf16x8*)&vB[((4 + ks) * 64 + lane) * 8];
      o0 = __builtin_amdgcn_mfma_f32_32x32x16_bf16(a, b0, o0, 0, 0, 0);
      o1 = __builtin_amdgcn_mfma_f32_32x32x16_bf16(a, b1, o1, 0, 0, 0);
    }
    float* op = Opart + (size_t)(bb * 64 + sc) * (NN * HH);
    const int h0 = lane & 31, h1 = 32 + (lane & 31);
#pragma unroll
    for (int reg = 0; reg < 16; ++reg) {
      int j = w * 32 + (reg & 3) + 8 * (reg >> 2) + 4 * (lane >> 5);
      op[j * HH + h0] = o0[reg];
      op[j * HH + h1] = o1[reg];
    }
  }
  grid.sync();

  // ================= phase 2: oy =================
  {
    float (*part)[4][64] = (float(*)[4][64])smem;
    const int b = blk >> 6;
    const int j0 = (blk & 63) * 2;
    const int h = tid & 63;
    const int q = tid >> 6;
#pragma unroll
    for (int jj = 0; jj < 2; ++jj) {
      float s = 0.f;
#pragma unroll
      for (int i = 0; i < 16; ++i)
        s += Opart[((size_t)(b * 64 + q * 16 + i) * NN + j0 + jj) * HH + h];
      part[jj][q][h] = s;
    }
    __syncthreads();
    if (tid < 128) {
      int jj = tid >> 6;
      int lane = tid & 63;
      float o = part[jj][0][lane] + part[jj][1][lane] + part[jj][2][lane] +
                part[jj][3][lane];
      float v = tanhf(o) * pw[lane];
#pragma unroll
      for (int off = 32; off > 0; off >>= 1) v += __shfl_down(v, off, 64);
      if (lane == 0) ynode[b * NN + j0 + jj] = v + pb[0];
    }
  }
  grid.sync();

  // ================= phase 3: final (64 t's per block) =================
  {
    float* yl = (float*)smem;          // 128 floats
    float* c = (float*)(smem + 512);   // 128 floats
    const int base = blk * 64;         // [0, B*T)
    const int b = base >> 12;
    if (tid < NN) yl[tid] = ynode[b * NN + tid];
    __syncthreads();
    if (tid < NN) {
      double acc = 0.0;
#pragma unroll 8
      for (int j = 0; j < NN; ++j)
        acc += (double)yl[j] * (double)Cmat[tid * NN + j];
      c[tid] = (float)(acc * ((tid == 0 ? 1.0 : 2.0) / NN));
    }
    __syncthreads();
    if (tid < 64) {
      const int idx = base + tid;
      float xf = x[idx] * (1.0f / XR);
      xf = fminf(1.0f, fmaxf(-1.0f, xf));
      double xh = (double)xf;
      double b1 = 0.0, b2 = 0.0;
      for (int m = NN - 1; m >= 1; --m) {
        double t = fma(2.0 * xh, b1, (double)c[m] - b2);
        b2 = b1;
        b1 = t;
      }
      y[idx] = (float)fma(xh, b1, (double)c[0] - b2);
    }
  }
}

extern "C" void kernel_launch(void* const* d_in, const int* in_sizes, int n_in,
                              void* d_out, int out_size, void* d_ws,
                              size_t ws_size, hipStream_t stream) {
  const float* x = (const float*)d_in[0];
  const float* emb = (const float*)d_in[1];
  const float* kw = (const float*)d_in[2];
  const float* kb = (const float*)d_in[3];
  const float* qw = (const float*)d_in[4];
  const float* qb = (const float*)d_in[5];
  const float* vw = (const float*)d_in[6];
  const float* pw = (const float*)d_in[7];
  const float* pb = (const float*)d_in[8];

  float* ws = (float*)d_ws;
  float* Opart = ws;                                      // 2M floats
  float* Cmat = ws + (2 << 20);                           // 16384
  unsigned short* qnA = (unsigned short*)(Cmat + 16384);  // 4096 float-slots
  unsigned int* Wfrag = (unsigned int*)(Cmat + 16384 + 4096);  // 32768 slots
  float* Sm_part = (float*)(Wfrag + 32768);               // 16384
  float* ynode = Sm_part + 16384;                         // 512
  float* y = (float*)d_out;

  void* args[] = {&x,  &emb,   &kw,   &kb,      &qw,    &qb,
                  &vw, &pw,    &pb,   &Wfrag,   &Cmat,  &qnA,
                  &Sm_part, &Opart, &ynode, &y};
  hipLaunchCooperativeKernel((void*)mega_kernel, dim3(256), dim3(256), args, 0,
                             stream);
}

// Round 10
// 137.973 us; speedup vs baseline: 1.6679x; 1.6679x over previous
//
#include <hip/hip_runtime.h>
#include <math.h>

// Problem constants (fixed by the reference setup_inputs)
#define BB 4
#define TT 4096
#define SS 4096
#define EE 512
#define HH 64
#define NN 128          // Chebyshev nodes / polynomial degree
#define XR 6.0f         // interpolation half-range for x

// Workspace layout (floats), NO aliasing (~8.5 MB):
//  Opart  : [B][64][N][H]  ws + 0      (2M)  partial O tiles
//  Cmat   : [N][N]         ws + 2M     (16384)
//  qnA    : bf16 A-frags   +16384      (4096 float-slots = 8192 bf16)
//  Wfrag  : bf16 B-frags   +4096       (32768 float-slots = 65536 bf16)
//  Sm_part: [B][32][N]     +32768      (16384)
//  ynode  : [B][N]         +16384      (512)
//
// R9 lesson (measured): cooperative grid.sync() costs ~50 us each on MI355X
// (8 non-coherent XCD L2s -> device-scope spin). Dispatch boundaries in the
// captured graph are ~2-5 us. Keep the 4-dispatch pipeline.

typedef __attribute__((ext_vector_type(8))) __bf16 bf16x8;
typedef __attribute__((ext_vector_type(16))) float f32x16;

__device__ __forceinline__ unsigned short f2b(float f) {
  unsigned int u = __float_as_uint(f);
  return (unsigned short)((u + 0x7FFFu + ((u >> 16) & 1u)) >> 16);  // RNE
}

// ---------------------------------------------------------------------------
// Kernel A (prep+sm fused):
//   blocks [0,64)    : Wfrag pack (kw||vw fp32 -> MFMA B-frag bf16)
//   blocks [64,128)  : Cmat[m][j] = cos(m*pi*(j+.5)/N)
//   blocks [128,160) : qnA bf16 A-frags of qn[j][h] = tanh(x_j*qw[h]+qb[h])
//   blocks [160,288) : Sm_part[b][chunk][m] = sum_{128 t} cos(m*acos(xhat_t))
// ---------------------------------------------------------------------------
__global__ __launch_bounds__(256) void prep_sm_kernel(
    const float* __restrict__ kw, const float* __restrict__ vw,
    const float* __restrict__ qw, const float* __restrict__ qb,
    const float* __restrict__ x, unsigned int* __restrict__ Wfrag,
    float* __restrict__ Cmat, unsigned short* __restrict__ qnA,
    float* __restrict__ Sm_part) {
  const int blk = blockIdx.x;
  if (blk < 64) {
    // Wfrag pack: ((nblk*32 + kstep)*64 + lane)*8 + j  (bf16 units)
    int idx = blk * 256 + threadIdx.x;  // [0, 16384)
    int jq = idx & 1;
    int l = (idx >> 1) & 63;
    int ks = (idx >> 7) & 31;
    int nb = idx >> 12;
    int n = nb * 32 + (l & 31);
    int k = ks * 16 + (l >> 5) * 8 + jq * 4;
    const float* row = (n < HH) ? (kw + n * EE + k) : (vw + (n - HH) * EE + k);
    float4 wv = *(const float4*)row;
    Wfrag[idx * 2] = (unsigned int)f2b(wv.x) | ((unsigned int)f2b(wv.y) << 16);
    Wfrag[idx * 2 + 1] =
        (unsigned int)f2b(wv.z) | ((unsigned int)f2b(wv.w) << 16);
  } else if (blk < 128) {
    int idx = (blk - 64) * 256 + threadIdx.x;  // [0, N*N)
    int m = idx >> 7;
    int j = idx & (NN - 1);
    Cmat[idx] = (float)cos((double)m * (M_PI * (j + 0.5) / NN));
  } else if (blk < 160) {
    int idx = (blk - 128) * 256 + threadIdx.x;  // [0, 8192)
    int h = idx & 63;
    int j = idx >> 6;
    double th = M_PI * (j + 0.5) / NN;
    float xj = (float)(XR * cos(th));
    float val = tanhf(fmaf(xj, qw[h], qb[h]));
    // A-frag position for element (m=j, k=h):
    int pos = (((j >> 5) * 4 + (h >> 4)) * 64 + (j & 31) + 32 * ((h >> 3) & 1)) * 8 +
              (h & 7);
    qnA[pos] = f2b(val);
  } else {
    __shared__ float theta[128];
    int blk2 = blk - 160;  // [0,128)
    int b = blk2 >> 5;
    int chunk = blk2 & 31;
    int t0 = chunk * 128;
    int tid = threadIdx.x;
    if (tid < 128) {
      float xh = x[b * TT + t0 + tid] * (1.0f / XR);
      xh = fminf(1.0f, fmaxf(-1.0f, xh));
      theta[tid] = acosf(xh);
    }
    __syncthreads();
    if (tid < 128) {
      float m = (float)tid;
      float acc = 0.f;
#pragma unroll 8
      for (int i = 0; i < 128; ++i) acc += cosf(m * theta[i]);
      Sm_part[(b * 32 + chunk) * NN + tid] = acc;
    }
  }
}

// ---------------------------------------------------------------------------
// Kernel B (kv+attn, all-MFMA). One block per 64-row s-chunk of one batch.
//  p0 : stage emb half-tile (32 rows) -> bf16 A-frags (32 KB LDS);
//       tid<128 also reduce Sm + compute wq
//  p1 : kv MFMA acc0; re-stage rows 32..63; kv MFMA acc1
//       (split staging halves LDS 69120->36352 B => 4 blocks/CU, was 2;
//        costs one extra Wfrag L2 re-read per block — R10 occupancy lever)
//  p2 : epilogue tanh -> ktB (B-frag, k=h,n=s) / vB (B-frag, k=s,n=h), bf16
//  p3 : GEMM1 MFMA l[j][s] (A=qnA global frags); e=exp(l/8); Z=sum_j wq_j*e
//  p4 : pack e*invZ -> eA (A-frag, m=j,k=s); GEMM2 MFMA -> Opart fp32
// LDS union: [0,32768) A_half / (ktB 8K | vB 8K | eA 16K); tail [32768,36352).
// ---------------------------------------------------------------------------
__global__ __launch_bounds__(256) void kvattn_kernel(
    const float* __restrict__ emb, const float* __restrict__ kb,
    const unsigned int* __restrict__ Wfrag, const unsigned short* __restrict__ qnA,
    const float* __restrict__ Cmat, const float* __restrict__ Sm_part,
    float* __restrict__ Opart) {
  __shared__ __align__(16) char smem[36352];
  unsigned short* A_half = (unsigned short*)smem;        // 32768 B (p0/p1)
  unsigned short* ktB = (unsigned short*)smem;           // 8192 B  (p2+)
  unsigned short* vB = (unsigned short*)(smem + 8192);   // 8192 B  (p2+)
  unsigned short* eA = (unsigned short*)(smem + 16384);  // 16384 B (p4)
  float* zred = (float*)(smem + 32768);                  // 64*9 floats (2304 B)
  float* wql = (float*)(smem + 35072);                   // 128 (512 B)
  float* izl = (float*)(smem + 35584);                   // 64  (256 B)
  float* sml = (float*)(smem + 35840);                   // 128 (512 B)

  const int tid = threadIdx.x;
  const int row0 = blockIdx.x * 64;  // [0, B*S)
  const int bb = row0 >> 12;
  const int sc = (row0 >> 6) & 63;
  const int w = tid >> 6;  // wave 0..3 (0,1=K cols; 2,3=V cols)
  const int lane = tid & 63;
  const bf16x8* Bf = (const bf16x8*)Wfrag;

  // ---- p0: stage A half 0 (rows 0..31), fp32 -> bf16 frags ----
  {
    int m = tid >> 3;  // 0..31 local row
    int c8 = tid & 7;
    const float* src = emb + (size_t)(row0 + m) * EE;
#pragma unroll
    for (int it = 0; it < 16; ++it) {
      int k = (c8 + it * 8) * 4;
      float4 v = *(const float4*)(src + k);
      int kstep = k >> 4;
      int l = m + 32 * ((k >> 3) & 1);
      int j = k & 7;
      unsigned int lo = (unsigned int)f2b(v.x) | ((unsigned int)f2b(v.y) << 16);
      unsigned int hi = (unsigned int)f2b(v.z) | ((unsigned int)f2b(v.w) << 16);
      *(uint2*)&A_half[(kstep * 64 + l) * 8 + j] = make_uint2(lo, hi);
    }
  }
  // p0b: Sm chunk-reduce (tid<128)
  if (tid < 128) {
    float s = 0.f;
#pragma unroll 8
    for (int c = 0; c < 32; ++c) s += Sm_part[(bb * 32 + c) * NN + tid];
    sml[tid] = s;
  }
  __syncthreads();
  // p0c: wq[j] (tid<128; fp32 — error ~1e-6 rel, audited)
  if (tid < 128) {
    float acc = sml[0] * (1.0f / NN);
    for (int m = 1; m < NN; ++m)
      acc = fmaf(sml[m] * (2.0f / NN), Cmat[m * NN + tid], acc);
    wql[tid] = acc;
  }

  // ---- p1a: kv MFMA, rows 0..31 -> acc0 ----
  f32x16 acc0 = {}, acc1 = {};
#pragma unroll 4
  for (int kstep = 0; kstep < 32; ++kstep) {
    bf16x8 bfr = Bf[(w * 32 + kstep) * 64 + lane];
    bf16x8 a0 = *(const bf16x8*)&A_half[(kstep * 64 + lane) * 8];
    acc0 = __builtin_amdgcn_mfma_f32_32x32x16_bf16(a0, bfr, acc0, 0, 0, 0);
  }
  __syncthreads();  // all waves done reading half 0
  // ---- p1b: stage A half 1 (rows 32..63) ----
  {
    int m = tid >> 3;
    int c8 = tid & 7;
    const float* src = emb + (size_t)(row0 + 32 + m) * EE;
#pragma unroll
    for (int it = 0; it < 16; ++it) {
      int k = (c8 + it * 8) * 4;
      float4 v = *(const float4*)(src + k);
      int kstep = k >> 4;
      int l = m + 32 * ((k >> 3) & 1);
      int j = k & 7;
      unsigned int lo = (unsigned int)f2b(v.x) | ((unsigned int)f2b(v.y) << 16);
      unsigned int hi = (unsigned int)f2b(v.z) | ((unsigned int)f2b(v.w) << 16);
      *(uint2*)&A_half[(kstep * 64 + l) * 8 + j] = make_uint2(lo, hi);
    }
  }
  __syncthreads();
  // ---- p1c: kv MFMA, rows 32..63 -> acc1 ----
#pragma unroll 4
  for (int kstep = 0; kstep < 32; ++kstep) {
    bf16x8 bfr = Bf[(w * 32 + kstep) * 64 + lane];
    bf16x8 a1 = *(const bf16x8*)&A_half[(kstep * 64 + lane) * 8];
    acc1 = __builtin_amdgcn_mfma_f32_32x32x16_bf16(a1, bfr, acc1, 0, 0, 0);
  }
  __syncthreads();  // A_half dead; ktB/vB/eA alias it

  // ---- p2: epilogue -> bf16 B-frags in LDS ----
  {
    const int n = w * 32 + (lane & 31);
    if (w < 2) {  // K half: element (k=h=n, n_dim=s)
      float kbv = kb[n];
      const int ks_h = n >> 4;
      const int off_h = 32 * ((n >> 3) & 1);
      const int jj_h = n & 7;
#pragma unroll
      for (int reg = 0; reg < 16; ++reg) {
        int sl = (reg & 3) + 8 * (reg >> 2) + 4 * (lane >> 5);  // s in [0,32)
        ktB[(ks_h * 64 + sl + off_h) * 8 + jj_h] = f2b(tanhf(acc0[reg] + kbv));
        ktB[((4 + ks_h) * 64 + sl + off_h) * 8 + jj_h] =
            f2b(tanhf(acc1[reg] + kbv));
      }
    } else {  // V half: element (k=s, n_dim=h)
      int h = n - 64;
      const int nb_h = h >> 5;
      const int lm = h & 31;
#pragma unroll
      for (int reg = 0; reg < 16; ++reg) {
        int sl = (reg & 3) + 8 * (reg >> 2) + 4 * (lane >> 5);
        int s1 = sl + 32;
        vB[((nb_h * 4 + (sl >> 4)) * 64 + lm + 32 * ((sl >> 3) & 1)) * 8 +
           (sl & 7)] = f2b(tanhf(acc0[reg]));
        vB[((nb_h * 4 + (s1 >> 4)) * 64 + lm + 32 * ((s1 >> 3) & 1)) * 8 +
           (s1 & 7)] = f2b(tanhf(acc1[reg]));
      }
    }
  }
  __syncthreads();

  // ---- p3: GEMM1 MFMA: l[j][s], j-block = w ----
  f32x16 l0 = {}, l1 = {};
#pragma unroll
  for (int ks = 0; ks < 4; ++ks) {
    bf16x8 a = *(const bf16x8*)(qnA + ((w * 4 + ks) * 64 + lane) * 8);
    bf16x8 b0 = *(const bf16x8*)&ktB[(ks * 64 + lane) * 8];
    bf16x8 b1 = *(const bf16x8*)&ktB[((4 + ks) * 64 + lane) * 8];
    l0 = __builtin_amdgcn_mfma_f32_32x32x16_bf16(a, b0, l0, 0, 0, 0);
    l1 = __builtin_amdgcn_mfma_f32_32x32x16_bf16(a, b1, l1, 0, 0, 0);
  }
  // exp + Z partials (j = w*32 + (reg&3)+8*(reg>>2)+4*(lane>>5))
  float e0[16], e1[16];
  float zp0 = 0.f, zp1 = 0.f;
#pragma unroll
  for (int r = 0; r < 4; ++r) {
    float4 wq4 = *(const float4*)&wql[w * 32 + 8 * r + 4 * (lane >> 5)];
    float wa[4] = {wq4.x, wq4.y, wq4.z, wq4.w};
#pragma unroll
    for (int c = 0; c < 4; ++c) {
      int reg = 4 * r + c;
      e0[reg] = __expf(l0[reg] * 0.125f);
      e1[reg] = __expf(l1[reg] * 0.125f);
      zp0 = fmaf(wa[c], e0[reg], zp0);
      zp1 = fmaf(wa[c], e1[reg], zp1);
    }
  }
  zred[(lane & 31) * 9 + w * 2 + (lane >> 5)] = zp0;
  zred[(32 + (lane & 31)) * 9 + w * 2 + (lane >> 5)] = zp1;
  __syncthreads();
  if (tid < 64) {
    float sum = 0.f;
#pragma unroll
    for (int k = 0; k < 8; ++k) sum += zred[tid * 9 + k];
    izl[tid] = 1.0f / sum;
  }
  __syncthreads();

  // ---- p4: pack e*invZ -> eA (A-frag: m=j, k=s), then GEMM2 MFMA ----
  {
    const int sA = lane & 31, sB = 32 + (lane & 31);
    const float izA = izl[sA], izB = izl[sB];
    const int ksA = sA >> 4, oA = 32 * ((sA >> 3) & 1), jA = sA & 7;
    const int ksB = sB >> 4, oB = 32 * ((sB >> 3) & 1), jB = sB & 7;
#pragma unroll
    for (int reg = 0; reg < 16; ++reg) {
      int jl = (reg & 3) + 8 * (reg >> 2) + 4 * (lane >> 5);  // j & 31
      eA[((w * 4 + ksA) * 64 + jl + oA) * 8 + jA] = f2b(e0[reg] * izA);
      eA[((w * 4 + ksB) * 64 + jl + oB) * 8 + jB] = f2b(e1[reg] * izB);
    }
  }
  __syncthreads();
  f32x16 o0 = {}, o1 = {};
#pragma unroll
  for (int ks = 0; ks < 4; ++ks) {
    bf16x8 a = *(const bf16x8*)&eA[((w * 4 + ks) * 64 + lane) * 8];
    bf16x8 b0 = *(const bf16x8*)&vB[(ks * 64 + lane) * 8];
    bf16x8 b1 = *(const bf16x8*)&vB[((4 + ks) * 64 + lane) * 8];
    o0 = __builtin_amdgcn_mfma_f32_32x32x16_bf16(a, b0, o0, 0, 0, 0);
    o1 = __builtin_amdgcn_mfma_f32_32x32x16_bf16(a, b1, o1, 0, 0, 0);
  }
  float* op = Opart + (size_t)(bb * 64 + sc) * (NN * HH);
  const int h0 = lane & 31, h1 = 32 + (lane & 31);
#pragma unroll
  for (int reg = 0; reg < 16; ++reg) {
    int j = w * 32 + (reg & 3) + 8 * (reg >> 2) + 4 * (lane >> 5);
    op[j * HH + h0] = o0[reg];
    op[j * HH + h1] = o1[reg];
  }
}

// ---------------------------------------------------------------------------
// Kernel C (oreduce+ynode): 256 blocks, block = (b, 2 j's); thread = (h, q):
//   each sums 16 sc's; LDS-reduce 4 partials; tanh*pw; wave-reduce -> ynode.
// ---------------------------------------------------------------------------
__global__ __launch_bounds__(256) void oy_kernel(const float* __restrict__ Opart,
                                                 const float* __restrict__ pw,
                                                 const float* __restrict__ pb,
                                                 float* __restrict__ ynode) {
  __shared__ float part[2][4][64];
  const int tid = threadIdx.x;
  const int b = blockIdx.x >> 6;
  const int j0 = (blockIdx.x & 63) * 2;
  const int h = tid & 63;
  const int q = tid >> 6;
#pragma unroll
  for (int jj = 0; jj < 2; ++jj) {
    float s = 0.f;
#pragma unroll
    for (int i = 0; i < 16; ++i)
      s += Opart[((size_t)(b * 64 + q * 16 + i) * NN + j0 + jj) * HH + h];
    part[jj][q][h] = s;
  }
  __syncthreads();
  if (tid < 128) {
    int jj = tid >> 6;
    int lane = tid & 63;
    float o = part[jj][0][lane] + part[jj][1][lane] + part[jj][2][lane] +
              part[jj][3][lane];
    float v = tanhf(o) * pw[lane];
#pragma unroll
    for (int off = 32; off > 0; off >>= 1) v += __shfl_down(v, off, 64);
    if (lane == 0) ynode[b * NN + j0 + jj] = v + pb[0];
  }
}

// ---------------------------------------------------------------------------
// Kernel D (coef+final fused): per block, recompute coef[b] in LDS (double-acc
// DCT, redundant across blocks — trivial), then Clenshaw per element.
// ---------------------------------------------------------------------------
__global__ __launch_bounds__(256) void final_kernel(
    const float* __restrict__ x, const float* __restrict__ ynode,
    const float* __restrict__ Cmat, float* __restrict__ y) {
  const int idx = blockIdx.x * 256 + threadIdx.x;  // [0, B*T)
  const int b = idx >> 12;
  __shared__ float yl[NN];
  __shared__ float c[NN];
  if (threadIdx.x < NN) yl[threadIdx.x] = ynode[b * NN + threadIdx.x];
  __syncthreads();
  if (threadIdx.x < NN) {
    int m = threadIdx.x;
    double acc = 0.0;
#pragma unroll 8
    for (int j = 0; j < NN; ++j)
      acc += (double)yl[j] * (double)Cmat[m * NN + j];
    c[m] = (float)(acc * ((m == 0 ? 1.0 : 2.0) / NN));
  }
  __syncthreads();
  float xf = x[idx] * (1.0f / XR);
  xf = fminf(1.0f, fmaxf(-1.0f, xf));
  double xh = (double)xf;
  double b1 = 0.0, b2 = 0.0;
  for (int m = NN - 1; m >= 1; --m) {
    double t = fma(2.0 * xh, b1, (double)c[m] - b2);
    b2 = b1;
    b1 = t;
  }
  y[idx] = (float)fma(xh, b1, (double)c[0] - b2);
}

extern "C" void kernel_launch(void* const* d_in, const int* in_sizes, int n_in,
                              void* d_out, int out_size, void* d_ws,
                              size_t ws_size, hipStream_t stream) {
  const float* x = (const float*)d_in[0];
  const float* emb = (const float*)d_in[1];
  const float* kw = (const float*)d_in[2];
  const float* kb = (const float*)d_in[3];
  const float* qw = (const float*)d_in[4];
  const float* qb = (const float*)d_in[5];
  const float* vw = (const float*)d_in[6];
  const float* pw = (const float*)d_in[7];
  const float* pb = (const float*)d_in[8];

  float* ws = (float*)d_ws;
  float* Opart = ws;                                   // 2M floats
  float* Cmat = ws + (2 << 20);                        // 16384
  unsigned short* qnA = (unsigned short*)(Cmat + 16384);  // 4096 float-slots
  unsigned int* Wfrag = (unsigned int*)(Cmat + 16384 + 4096);  // 32768 slots
  float* Sm_part = (float*)(Wfrag + 32768);            // 16384
  float* ynode = Sm_part + 16384;                      // 512
  float* y = (float*)d_out;

  prep_sm_kernel<<<288, 256, 0, stream>>>(kw, vw, qw, qb, x, Wfrag, Cmat, qnA,
                                          Sm_part);
  kvattn_kernel<<<BB * SS / 64, 256, 0, stream>>>(emb, kb, Wfrag, qnA, Cmat,
                                                  Sm_part, Opart);
  oy_kernel<<<BB * NN / 2, 256, 0, stream>>>(Opart, pw, pb, ynode);
  final_kernel<<<BB * TT / 256, 256, 0, stream>>>(x, ynode, Cmat, y);
}

// Round 11
// 135.254 us; speedup vs baseline: 1.7014x; 1.0201x over previous
//
#include <hip/hip_runtime.h>
#include <math.h>

// Problem constants (fixed by the reference setup_inputs)
#define BB 4
#define TT 4096
#define SS 4096
#define EE 512
#define HH 64
#define NN 128          // Chebyshev nodes / polynomial degree
#define XR 6.0f         // interpolation half-range for x

// Workspace layout (floats), NO aliasing (~8.5 MB):
//  Opart  : [B][64][N][H]  ws + 0      (2M)  partial O tiles
//  Cmat   : [N][N]         ws + 2M     (16384)
//  qnA    : bf16 A-frags   +16384      (4096 float-slots = 8192 bf16)
//  Wfrag  : bf16 B-frags   +4096       (32768 float-slots = 65536 bf16)
//  Sm_part: [B][32][N]     +32768      (16384)
//  ynode  : [B][N]         +16384      (512)
//
// Session lessons (measured):
//  R9 : cooperative grid.sync() ~50 us each on MI355X (8 non-coherent XCD
//       L2s -> device-scope spin). Graph dispatch boundaries are ~5 us.
//  R10: kvattn grid = 256 blocks on 256 CUs -> occupancy is GRID-limited at
//       1 block/CU; LDS reduction (69->36 KB) buys nothing and the extra
//       barriers + duplicate Wfrag pass cost +2.7 us. Keep 64 KB staging.

typedef __attribute__((ext_vector_type(8))) __bf16 bf16x8;
typedef __attribute__((ext_vector_type(16))) float f32x16;

__device__ __forceinline__ unsigned short f2b(float f) {
  unsigned int u = __float_as_uint(f);
  return (unsigned short)((u + 0x7FFFu + ((u >> 16) & 1u)) >> 16);  // RNE
}

// ---------------------------------------------------------------------------
// Kernel A (prep+sm fused):
//   blocks [0,64)    : Wfrag pack (kw||vw fp32 -> MFMA B-frag bf16)
//   blocks [64,128)  : Cmat[m][j] = cos(m*pi*(j+.5)/N)
//   blocks [128,160) : qnA bf16 A-frags of qn[j][h] = tanh(x_j*qw[h]+qb[h])
//   blocks [160,288) : Sm_part[b][chunk][m] = sum_{128 t} cos(m*acos(xhat_t))
// ---------------------------------------------------------------------------
__global__ __launch_bounds__(256) void prep_sm_kernel(
    const float* __restrict__ kw, const float* __restrict__ vw,
    const float* __restrict__ qw, const float* __restrict__ qb,
    const float* __restrict__ x, unsigned int* __restrict__ Wfrag,
    float* __restrict__ Cmat, unsigned short* __restrict__ qnA,
    float* __restrict__ Sm_part) {
  const int blk = blockIdx.x;
  if (blk < 64) {
    // Wfrag pack: ((nblk*32 + kstep)*64 + lane)*8 + j  (bf16 units)
    int idx = blk * 256 + threadIdx.x;  // [0, 16384)
    int jq = idx & 1;
    int l = (idx >> 1) & 63;
    int ks = (idx >> 7) & 31;
    int nb = idx >> 12;
    int n = nb * 32 + (l & 31);
    int k = ks * 16 + (l >> 5) * 8 + jq * 4;
    const float* row = (n < HH) ? (kw + n * EE + k) : (vw + (n - HH) * EE + k);
    float4 wv = *(const float4*)row;
    Wfrag[idx * 2] = (unsigned int)f2b(wv.x) | ((unsigned int)f2b(wv.y) << 16);
    Wfrag[idx * 2 + 1] =
        (unsigned int)f2b(wv.z) | ((unsigned int)f2b(wv.w) << 16);
  } else if (blk < 128) {
    int idx = (blk - 64) * 256 + threadIdx.x;  // [0, N*N)
    int m = idx >> 7;
    int j = idx & (NN - 1);
    Cmat[idx] = (float)cos((double)m * (M_PI * (j + 0.5) / NN));
  } else if (blk < 160) {
    int idx = (blk - 128) * 256 + threadIdx.x;  // [0, 8192)
    int h = idx & 63;
    int j = idx >> 6;
    double th = M_PI * (j + 0.5) / NN;
    float xj = (float)(XR * cos(th));
    float val = tanhf(fmaf(xj, qw[h], qb[h]));
    // A-frag position for element (m=j, k=h):
    int pos = (((j >> 5) * 4 + (h >> 4)) * 64 + (j & 31) + 32 * ((h >> 3) & 1)) * 8 +
              (h & 7);
    qnA[pos] = f2b(val);
  } else {
    __shared__ float theta[128];
    int blk2 = blk - 160;  // [0,128)
    int b = blk2 >> 5;
    int chunk = blk2 & 31;
    int t0 = chunk * 128;
    int tid = threadIdx.x;
    if (tid < 128) {
      float xh = x[b * TT + t0 + tid] * (1.0f / XR);
      xh = fminf(1.0f, fmaxf(-1.0f, xh));
      theta[tid] = acosf(xh);
    }
    __syncthreads();
    if (tid < 128) {
      float m = (float)tid;
      float acc = 0.f;
#pragma unroll 8
      for (int i = 0; i < 128; ++i) acc += cosf(m * theta[i]);
      Sm_part[(b * 32 + chunk) * NN + tid] = acc;
    }
  }
}

// ---------------------------------------------------------------------------
// Kernel B (kv+attn, all-MFMA). One block per 64-row s-chunk of one batch.
//  p0 : stage emb -> bf16 A-frags (LDS, full 64 KB); tid<128 reduce Sm + wq
//  p1 : kv MFMA (M=64 s, N=128 = K||V cols, K=512)
//  p2 : epilogue tanh -> ktB (B-frag, k=h,n=s) / vB (B-frag, k=s,n=h), bf16
//       (alias the dead A_lds region)
//  p3 : GEMM1 MFMA l[j][s] (A=qnA global frags); e=exp(l/8); Z=sum_j wq_j*e
//  p4 : pack e*invZ -> eA (A-frag, m=j,k=s); GEMM2 MFMA -> Opart fp32
// LDS: [0,65536) A_lds / frag buffers; [65536,69120) reduction tail.
// ---------------------------------------------------------------------------
__global__ __launch_bounds__(256) void kvattn_kernel(
    const float* __restrict__ emb, const float* __restrict__ kb,
    const unsigned int* __restrict__ Wfrag, const unsigned short* __restrict__ qnA,
    const float* __restrict__ Cmat, const float* __restrict__ Sm_part,
    float* __restrict__ Opart) {
  __shared__ __align__(16) char smem[69120];
  unsigned short* A_lds = (unsigned short*)smem;         // 65536 B (p0/p1)
  unsigned short* ktB = (unsigned short*)smem;           // 8192 B  (p2+)
  unsigned short* vB = (unsigned short*)(smem + 8192);   // 8192 B  (p2+)
  unsigned short* eA = (unsigned short*)(smem + 16384);  // 16384 B (p4)
  float* zred = (float*)(smem + 65536);                  // 64*9 floats (2304 B)
  float* wql = (float*)(smem + 67840);                   // 128 (512 B)
  float* izl = (float*)(smem + 68352);                   // 64  (256 B)
  float* sml = (float*)(smem + 68608);                   // 128 (512 B)

  const int tid = threadIdx.x;
  const int row0 = blockIdx.x * 64;  // [0, B*S)
  const int bb = row0 >> 12;
  const int sc = (row0 >> 6) & 63;

  // ---- p0: stage A (64 rows x 512 k), fp32 -> bf16 frags ----
#pragma unroll
  for (int mb = 0; mb < 2; ++mb) {
    int m = tid >> 3;  // 0..31 local row
    int c8 = tid & 7;
    const float* src = emb + (size_t)(row0 + mb * 32 + m) * EE;
    unsigned short* dst = A_lds + mb * 16384;
#pragma unroll
    for (int it = 0; it < 16; ++it) {
      int k = (c8 + it * 8) * 4;
      float4 v = *(const float4*)(src + k);
      int kstep = k >> 4;
      int lane = m + 32 * ((k >> 3) & 1);
      int j = k & 7;
      unsigned int lo = (unsigned int)f2b(v.x) | ((unsigned int)f2b(v.y) << 16);
      unsigned int hi = (unsigned int)f2b(v.z) | ((unsigned int)f2b(v.w) << 16);
      *(uint2*)&dst[(kstep * 64 + lane) * 8 + j] = make_uint2(lo, hi);
    }
  }
  // p0b: Sm chunk-reduce (tid<128)
  if (tid < 128) {
    float s = 0.f;
#pragma unroll 8
    for (int c = 0; c < 32; ++c) s += Sm_part[(bb * 32 + c) * NN + tid];
    sml[tid] = s;
  }
  __syncthreads();
  // p0c: wq[j] (tid<128; fp32 — error ~1e-6 rel, audited)
  if (tid < 128) {
    float acc = sml[0] * (1.0f / NN);
    for (int m = 1; m < NN; ++m)
      acc = fmaf(sml[m] * (2.0f / NN), Cmat[m * NN + tid], acc);
    wql[tid] = acc;
  }

  // ---- p1: kv MFMA ----
  const int w = tid >> 6;  // wave 0..3 (0,1=K cols; 2,3=V cols)
  const int lane = tid & 63;
  f32x16 acc0 = {}, acc1 = {};
  const bf16x8* Bf = (const bf16x8*)Wfrag;
#pragma unroll 4
  for (int kstep = 0; kstep < 32; ++kstep) {
    bf16x8 bfr = Bf[(w * 32 + kstep) * 64 + lane];
    bf16x8 a0 = *(const bf16x8*)&A_lds[(kstep * 64 + lane) * 8];
    bf16x8 a1 = *(const bf16x8*)&A_lds[16384 + (kstep * 64 + lane) * 8];
    acc0 = __builtin_amdgcn_mfma_f32_32x32x16_bf16(a0, bfr, acc0, 0, 0, 0);
    acc1 = __builtin_amdgcn_mfma_f32_32x32x16_bf16(a1, bfr, acc1, 0, 0, 0);
  }
  __syncthreads();  // A_lds dead; ktB/vB/eA alias it

  // ---- p2: epilogue -> bf16 B-frags in LDS ----
  {
    const int n = w * 32 + (lane & 31);
    if (w < 2) {  // K half: element (k=h=n, n_dim=s)
      float kbv = kb[n];
      const int ks_h = n >> 4;
      const int off_h = 32 * ((n >> 3) & 1);
      const int jj_h = n & 7;
#pragma unroll
      for (int reg = 0; reg < 16; ++reg) {
        int sl = (reg & 3) + 8 * (reg >> 2) + 4 * (lane >> 5);  // s in [0,32)
        ktB[(ks_h * 64 + sl + off_h) * 8 + jj_h] = f2b(tanhf(acc0[reg] + kbv));
        ktB[((4 + ks_h) * 64 + sl + off_h) * 8 + jj_h] =
            f2b(tanhf(acc1[reg] + kbv));
      }
    } else {  // V half: element (k=s, n_dim=h)
      int h = n - 64;
      const int nb_h = h >> 5;
      const int lm = h & 31;
#pragma unroll
      for (int reg = 0; reg < 16; ++reg) {
        int sl = (reg & 3) + 8 * (reg >> 2) + 4 * (lane >> 5);
        int s1 = sl + 32;
        vB[((nb_h * 4 + (sl >> 4)) * 64 + lm + 32 * ((sl >> 3) & 1)) * 8 +
           (sl & 7)] = f2b(tanhf(acc0[reg]));
        vB[((nb_h * 4 + (s1 >> 4)) * 64 + lm + 32 * ((s1 >> 3) & 1)) * 8 +
           (s1 & 7)] = f2b(tanhf(acc1[reg]));
      }
    }
  }
  __syncthreads();

  // ---- p3: GEMM1 MFMA: l[j][s], j-block = w ----
  f32x16 l0 = {}, l1 = {};
#pragma unroll
  for (int ks = 0; ks < 4; ++ks) {
    bf16x8 a = *(const bf16x8*)(qnA + ((w * 4 + ks) * 64 + lane) * 8);
    bf16x8 b0 = *(const bf16x8*)&ktB[(ks * 64 + lane) * 8];
    bf16x8 b1 = *(const bf16x8*)&ktB[((4 + ks) * 64 + lane) * 8];
    l0 = __builtin_amdgcn_mfma_f32_32x32x16_bf16(a, b0, l0, 0, 0, 0);
    l1 = __builtin_amdgcn_mfma_f32_32x32x16_bf16(a, b1, l1, 0, 0, 0);
  }
  // exp + Z partials (j = w*32 + (reg&3)+8*(reg>>2)+4*(lane>>5))
  float e0[16], e1[16];
  float zp0 = 0.f, zp1 = 0.f;
#pragma unroll
  for (int r = 0; r < 4; ++r) {
    float4 wq4 = *(const float4*)&wql[w * 32 + 8 * r + 4 * (lane >> 5)];
    float wa[4] = {wq4.x, wq4.y, wq4.z, wq4.w};
#pragma unroll
    for (int c = 0; c < 4; ++c) {
      int reg = 4 * r + c;
      e0[reg] = __expf(l0[reg] * 0.125f);
      e1[reg] = __expf(l1[reg] * 0.125f);
      zp0 = fmaf(wa[c], e0[reg], zp0);
      zp1 = fmaf(wa[c], e1[reg], zp1);
    }
  }
  zred[(lane & 31) * 9 + w * 2 + (lane >> 5)] = zp0;
  zred[(32 + (lane & 31)) * 9 + w * 2 + (lane >> 5)] = zp1;
  __syncthreads();
  if (tid < 64) {
    float sum = 0.f;
#pragma unroll
    for (int k = 0; k < 8; ++k) sum += zred[tid * 9 + k];
    izl[tid] = 1.0f / sum;
  }
  __syncthreads();

  // ---- p4: pack e*invZ -> eA (A-frag: m=j, k=s), then GEMM2 MFMA ----
  {
    const int sA = lane & 31, sB = 32 + (lane & 31);
    const float izA = izl[sA], izB = izl[sB];
    const int ksA = sA >> 4, oA = 32 * ((sA >> 3) & 1), jA = sA & 7;
    const int ksB = sB >> 4, oB = 32 * ((sB >> 3) & 1), jB = sB & 7;
#pragma unroll
    for (int reg = 0; reg < 16; ++reg) {
      int jl = (reg & 3) + 8 * (reg >> 2) + 4 * (lane >> 5);  // j & 31
      eA[((w * 4 + ksA) * 64 + jl + oA) * 8 + jA] = f2b(e0[reg] * izA);
      eA[((w * 4 + ksB) * 64 + jl + oB) * 8 + jB] = f2b(e1[reg] * izB);
    }
  }
  __syncthreads();
  f32x16 o0 = {}, o1 = {};
#pragma unroll
  for (int ks = 0; ks < 4; ++ks) {
    bf16x8 a = *(const bf16x8*)&eA[((w * 4 + ks) * 64 + lane) * 8];
    bf16x8 b0 = *(const bf16x8*)&vB[(ks * 64 + lane) * 8];
    bf16x8 b1 = *(const bf16x8*)&vB[((4 + ks) * 64 + lane) * 8];
    o0 = __builtin_amdgcn_mfma_f32_32x32x16_bf16(a, b0, o0, 0, 0, 0);
    o1 = __builtin_amdgcn_mfma_f32_32x32x16_bf16(a, b1, o1, 0, 0, 0);
  }
  float* op = Opart + (size_t)(bb * 64 + sc) * (NN * HH);
  const int h0 = lane & 31, h1 = 32 + (lane & 31);
#pragma unroll
  for (int reg = 0; reg < 16; ++reg) {
    int j = w * 32 + (reg & 3) + 8 * (reg >> 2) + 4 * (lane >> 5);
    op[j * HH + h0] = o0[reg];
    op[j * HH + h1] = o1[reg];
  }
}

// ---------------------------------------------------------------------------
// Kernel C (oreduce+ynode): 256 blocks, block = (b, 2 j's); thread = (h, q):
//   each sums 16 sc's; LDS-reduce 4 partials; tanh*pw; wave-reduce -> ynode.
// ---------------------------------------------------------------------------
__global__ __launch_bounds__(256) void oy_kernel(const float* __restrict__ Opart,
                                                 const float* __restrict__ pw,
                                                 const float* __restrict__ pb,
                                                 float* __restrict__ ynode) {
  __shared__ float part[2][4][64];
  const int tid = threadIdx.x;
  const int b = blockIdx.x >> 6;
  const int j0 = (blockIdx.x & 63) * 2;
  const int h = tid & 63;
  const int q = tid >> 6;
#pragma unroll
  for (int jj = 0; jj < 2; ++jj) {
    float s = 0.f;
#pragma unroll
    for (int i = 0; i < 16; ++i)
      s += Opart[((size_t)(b * 64 + q * 16 + i) * NN + j0 + jj) * HH + h];
    part[jj][q][h] = s;
  }
  __syncthreads();
  if (tid < 128) {
    int jj = tid >> 6;
    int lane = tid & 63;
    float o = part[jj][0][lane] + part[jj][1][lane] + part[jj][2][lane] +
              part[jj][3][lane];
    float v = tanhf(o) * pw[lane];
#pragma unroll
    for (int off = 32; off > 0; off >>= 1) v += __shfl_down(v, off, 64);
    if (lane == 0) ynode[b * NN + j0 + jj] = v + pb[0];
  }
}

// ---------------------------------------------------------------------------
// Kernel D (coef+final fused): per block, recompute coef[b] in LDS (double-acc
// DCT, redundant across blocks — trivial), then Clenshaw per element.
// ---------------------------------------------------------------------------
__global__ __launch_bounds__(256) void final_kernel(
    const float* __restrict__ x, const float* __restrict__ ynode,
    const float* __restrict__ Cmat, float* __restrict__ y) {
  const int idx = blockIdx.x * 256 + threadIdx.x;  // [0, B*T)
  const int b = idx >> 12;
  __shared__ float yl[NN];
  __shared__ float c[NN];
  if (threadIdx.x < NN) yl[threadIdx.x] = ynode[b * NN + threadIdx.x];
  __syncthreads();
  if (threadIdx.x < NN) {
    int m = threadIdx.x;
    double acc = 0.0;
#pragma unroll 8
    for (int j = 0; j < NN; ++j)
      acc += (double)yl[j] * (double)Cmat[m * NN + j];
    c[m] = (float)(acc * ((m == 0 ? 1.0 : 2.0) / NN));
  }
  __syncthreads();
  float xf = x[idx] * (1.0f / XR);
  xf = fminf(1.0f, fmaxf(-1.0f, xf));
  double xh = (double)xf;
  double b1 = 0.0, b2 = 0.0;
  for (int m = NN - 1; m >= 1; --m) {
    double t = fma(2.0 * xh, b1, (double)c[m] - b2);
    b2 = b1;
    b1 = t;
  }
  y[idx] = (float)fma(xh, b1, (double)c[0] - b2);
}

extern "C" void kernel_launch(void* const* d_in, const int* in_sizes, int n_in,
                              void* d_out, int out_size, void* d_ws,
                              size_t ws_size, hipStream_t stream) {
  const float* x = (const float*)d_in[0];
  const float* emb = (const float*)d_in[1];
  const float* kw = (const float*)d_in[2];
  const float* kb = (const float*)d_in[3];
  const float* qw = (const float*)d_in[4];
  const float* qb = (const float*)d_in[5];
  const float* vw = (const float*)d_in[6];
  const float* pw = (const float*)d_in[7];
  const float* pb = (const float*)d_in[8];

  float* ws = (float*)d_ws;
  float* Opart = ws;                                   // 2M floats
  float* Cmat = ws + (2 << 20);                        // 16384
  unsigned short* qnA = (unsigned short*)(Cmat + 16384);  // 4096 float-slots
  unsigned int* Wfrag = (unsigned int*)(Cmat + 16384 + 4096);  // 32768 slots
  float* Sm_part = (float*)(Wfrag + 32768);            // 16384
  float* ynode = Sm_part + 16384;                      // 512
  float* y = (float*)d_out;

  prep_sm_kernel<<<288, 256, 0, stream>>>(kw, vw, qw, qb, x, Wfrag, Cmat, qnA,
                                          Sm_part);
  kvattn_kernel<<<BB * SS / 64, 256, 0, stream>>>(emb, kb, Wfrag, qnA, Cmat,
                                                  Sm_part, Opart);
  oy_kernel<<<BB * NN / 2, 256, 0, stream>>>(Opart, pw, pb, ynode);
  final_kernel<<<BB * TT / 256, 256, 0, stream>>>(x, ynode, Cmat, y);
}